// Round 1
// baseline (1165.471 us; speedup 1.0000x reference)
//
#include <hip/hip_runtime.h>
#include <math.h>

// Problem constants
#define BB  2
#define SS  2048
#define DD  1024
#define HH  16
#define DKK 64

constexpr float kScale = 0.125f;  // 1/sqrt(64)

// ---------------------------------------------------------------------------
// Projection GEMM: C[M,N] = A[M,K] @ W[K,N] + bias
// M = B*S = 4096, N = K = 1024. BM=BN=64, BK=16, 256 threads, 4x4 microtile.
// MODE 0: plain row-major output (final O-projection)
// MODE 1: RoPE + scatter to [B,H,S,DK]   (Q,K)
// MODE 2: scatter to [B,H,S,DK], no RoPE (V)
// ---------------------------------------------------------------------------
template <int MODE>
__global__ __launch_bounds__(256) void gemm_proj_kernel(
    const float* __restrict__ A, const float* __restrict__ W,
    const float* __restrict__ bias, const int* __restrict__ pos,
    float* __restrict__ out) {
  __shared__ float As[16][65];  // [k][m], +1 pad
  __shared__ float Bs[16][65];  // [k][n], +1 pad

  const int t  = threadIdx.x;
  const int tx = t & 15;   // col group (4 cols each)
  const int ty = t >> 4;   // row group (4 rows each)
  const int bm = blockIdx.y * 64;
  const int bn = blockIdx.x * 64;

  float acc[4][4] = {};

  for (int kt = 0; kt < DD; kt += 16) {
    // Load A tile: 64 rows x 16 k (coalesced in 16-lane segments)
    {
      const int k  = t & 15;
      const int m0 = t >> 4;  // 0..15
#pragma unroll
      for (int i = 0; i < 4; i++) {
        const int m = m0 + i * 16;
        As[k][m] = A[(size_t)(bm + m) * DD + kt + k];
      }
    }
    // Load B tile: 16 k x 64 n (coalesced over n)
    {
      const int n  = t & 63;
      const int k0 = t >> 6;  // 0..3
#pragma unroll
      for (int i = 0; i < 4; i++) {
        const int k = k0 + i * 4;
        Bs[k][n] = W[(size_t)(kt + k) * DD + bn + n];
      }
    }
    __syncthreads();

#pragma unroll
    for (int kk = 0; kk < 16; kk++) {
      float a[4], b4[4];
#pragma unroll
      for (int i = 0; i < 4; i++) a[i] = As[kk][ty * 4 + i];
#pragma unroll
      for (int j = 0; j < 4; j++) b4[j] = Bs[kk][tx * 4 + j];
#pragma unroll
      for (int i = 0; i < 4; i++)
#pragma unroll
        for (int j = 0; j < 4; j++) acc[i][j] += a[i] * b4[j];
    }
    __syncthreads();
  }

  // Epilogue: bias, then mode-specific write
  const int n0 = bn + tx * 4;
#pragma unroll
  for (int i = 0; i < 4; i++)
#pragma unroll
    for (int j = 0; j < 4; j++) acc[i][j] += bias[n0 + j];

  if (MODE == 0) {
#pragma unroll
    for (int i = 0; i < 4; i++) {
      const int m = bm + ty * 4 + i;
#pragma unroll
      for (int j = 0; j < 4; j++) out[(size_t)m * DD + n0 + j] = acc[i][j];
    }
  } else {
    const int h   = n0 / DKK;     // constant within block (bn multiple of 64)
    const int dk0 = n0 % DKK;     // = tx*4, even
#pragma unroll
    for (int i = 0; i < 4; i++) {
      const int m = bm + ty * 4 + i;  // global token index
      const int b = m / SS;
      const int s = m % SS;
      if (MODE == 1) {
        const float p = (float)pos[m];
#pragma unroll
        for (int jp = 0; jp < 2; jp++) {
          const int dk = dk0 + jp * 2;       // even element of the pair
          const int pi = dk >> 1;            // pair index 0..31
          const float inv = __powf(10000.0f, -(float)(2 * pi) / (float)DKK);
          const float ang = p * inv;
          float sn, cs;
          __sincosf(ang, &sn, &cs);
          const float t1 = acc[i][jp * 2];
          const float t2 = acc[i][jp * 2 + 1];
          acc[i][jp * 2]     = t1 * cs - t2 * sn;
          acc[i][jp * 2 + 1] = t1 * sn + t2 * cs;
        }
      }
      float* op = out + ((size_t)(b * HH + h) * SS + s) * DKK + dk0;
#pragma unroll
      for (int j = 0; j < 4; j++) op[j] = acc[i][j];
    }
  }
}

// ---------------------------------------------------------------------------
// Flash attention (causal, online softmax). One block = (bh, 64-row Q tile).
// q,k,v in [B,H,S,DK]; o written in [B,S,H,DK] (= [B,S,D] token-major).
// ---------------------------------------------------------------------------
__global__ __launch_bounds__(256) void flash_attn_kernel(
    const float* __restrict__ q, const float* __restrict__ k,
    const float* __restrict__ v, float* __restrict__ o) {
  __shared__ float qsT[64][68];  // [dk][r]
  __shared__ float ksT[64][68];  // [dk][j]
  __shared__ float vs[64][68];   // [j][dk]
  __shared__ float sT[64][68];   // [j][r] scores, then probs
  __shared__ float mrow[64], lrow[64], arow[64];

  const int bh = blockIdx.x;   // 0..31
  const int qt = blockIdx.y;   // 0..31
  const int t  = threadIdx.x;
  const int r0 = (t >> 4) * 4;  // 0..60
  const int c0 = (t & 15) * 4;  // 0..60

  const float* qb = q + (size_t)bh * SS * DKK;
  const float* kb = k + (size_t)bh * SS * DKK;
  const float* vb = v + (size_t)bh * SS * DKK;

  // Load Q tile transposed
#pragma unroll 4
  for (int i = 0; i < 16; i++) {
    const int idx = t + 256 * i;  // 0..4095
    const int r  = idx >> 6;
    const int dk = idx & 63;
    qsT[dk][r] = qb[(size_t)(qt * 64 + r) * DKK + dk];
  }
  if (t < 64) {
    mrow[t] = -1e30f;
    lrow[t] = 0.0f;
  }
  float oacc[4][4] = {};
  __syncthreads();

  for (int kt = 0; kt <= qt; kt++) {
    // Load K (transposed) and V tiles
#pragma unroll 4
    for (int i = 0; i < 16; i++) {
      const int idx = t + 256 * i;
      const int j  = idx >> 6;
      const int dk = idx & 63;
      const size_t g = (size_t)(kt * 64 + j) * DKK + dk;
      ksT[dk][j] = kb[g];
      vs[j][dk]  = vb[g];
    }
    __syncthreads();

    // Scores micro-tile: s[r0..+3][c0..+3]
    float sc[4][4] = {};
    for (int kk = 0; kk < 64; kk++) {
      float a[4], b4[4];
#pragma unroll
      for (int i = 0; i < 4; i++) a[i] = qsT[kk][r0 + i];
#pragma unroll
      for (int j = 0; j < 4; j++) b4[j] = ksT[kk][c0 + j];
#pragma unroll
      for (int i = 0; i < 4; i++)
#pragma unroll
        for (int j = 0; j < 4; j++) sc[i][j] += a[i] * b4[j];
    }
    // Scale + causal mask, write transposed scores sT[j][r]
    const bool diag = (kt == qt);
#pragma unroll
    for (int j = 0; j < 4; j++)
#pragma unroll
      for (int i = 0; i < 4; i++) {
        float sv = sc[i][j] * kScale;
        if (diag && (c0 + j) > (r0 + i)) sv = -1e30f;
        sT[c0 + j][r0 + i] = sv;
      }
    __syncthreads();

    // Online softmax: thread t<64 owns row t
    if (t < 64) {
      const float m_old = mrow[t];
      float mx = m_old;
      for (int j = 0; j < 64; j++) mx = fmaxf(mx, sT[j][t]);
      const float alpha = __expf(m_old - mx);
      float l = lrow[t] * alpha;
      for (int j = 0; j < 64; j++) {
        const float pj = __expf(sT[j][t] - mx);
        sT[j][t] = pj;
        l += pj;
      }
      mrow[t] = mx;
      lrow[t] = l;
      arow[t] = alpha;
    }
    __syncthreads();

    // PV: rescale accumulator, then O += P^T-read * V
    float al[4];
#pragma unroll
    for (int i = 0; i < 4; i++) al[i] = arow[r0 + i];
#pragma unroll
    for (int i = 0; i < 4; i++)
#pragma unroll
      for (int d = 0; d < 4; d++) oacc[i][d] *= al[i];
    for (int j = 0; j < 64; j++) {
      float p4[4], v4[4];
#pragma unroll
      for (int i = 0; i < 4; i++) p4[i] = sT[j][r0 + i];
#pragma unroll
      for (int d = 0; d < 4; d++) v4[d] = vs[j][c0 + d];
#pragma unroll
      for (int i = 0; i < 4; i++)
#pragma unroll
        for (int d = 0; d < 4; d++) oacc[i][d] += p4[i] * v4[d];
    }
    __syncthreads();  // protect ksT/vs/sT before next tile overwrites them
  }

  // Epilogue: divide by l, write O in [B,S,H,DK]
  const int b = bh / HH;
  const int h = bh % HH;
#pragma unroll
  for (int i = 0; i < 4; i++) {
    const int s = qt * 64 + r0 + i;
    const float inv_l = 1.0f / lrow[r0 + i];
    float* op = o + ((size_t)(b * SS + s) * HH + h) * DKK + c0;
#pragma unroll
    for (int d = 0; d < 4; d++) op[d] = oacc[i][d] * inv_l;
  }
}

// ---------------------------------------------------------------------------
extern "C" void kernel_launch(void* const* d_in, const int* in_sizes, int n_in,
                              void* d_out, int out_size, void* d_ws,
                              size_t ws_size, hipStream_t stream) {
  const float* x  = (const float*)d_in[0];
  const int*   pos = (const int*)d_in[1];
  const float* Wq = (const float*)d_in[2];
  const float* bq = (const float*)d_in[3];
  const float* Wk = (const float*)d_in[4];
  const float* bk = (const float*)d_in[5];
  const float* Wv = (const float*)d_in[6];
  const float* bv = (const float*)d_in[7];
  const float* Wo = (const float*)d_in[8];
  const float* bo = (const float*)d_in[9];
  float* out = (float*)d_out;

  const size_t nElem = (size_t)BB * SS * DD;  // 4,194,304 floats = 16 MB
  float* q_ws = (float*)d_ws;
  float* k_ws = q_ws + nElem;
  float* v_ws = k_ws + nElem;
  float* o_ws = v_ws + nElem;  // total 64 MB workspace

  dim3 gemm_grid(DD / 64, (BB * SS) / 64);  // (16, 64)
  gemm_proj_kernel<1><<<gemm_grid, 256, 0, stream>>>(x, Wq, bq, pos, q_ws);
  gemm_proj_kernel<1><<<gemm_grid, 256, 0, stream>>>(x, Wk, bk, pos, k_ws);
  gemm_proj_kernel<2><<<gemm_grid, 256, 0, stream>>>(x, Wv, bv, pos, v_ws);

  flash_attn_kernel<<<dim3(BB * HH, SS / 64), 256, 0, stream>>>(q_ws, k_ws,
                                                                v_ws, o_ws);

  gemm_proj_kernel<0><<<gemm_grid, 256, 0, stream>>>(o_ws, Wo, bo, pos, out);
}

// Round 2
// 572.526 us; speedup vs baseline: 2.0357x; 2.0357x over previous
//
#include <hip/hip_runtime.h>
#include <math.h>

// Problem constants
#define BB  2
#define SS  2048
#define DD  1024
#define HH  16
#define DKK 64

constexpr float kScale = 0.125f;  // 1/sqrt(64)

typedef __bf16 bf16x8 __attribute__((ext_vector_type(8)));
typedef __bf16 bf16x4 __attribute__((ext_vector_type(4)));
typedef float f32x4 __attribute__((ext_vector_type(4)));

// Async global->LDS, 16 B per lane. LDS dest is wave-uniform base + lane*16.
__device__ __forceinline__ void async_copy16(const void* g, void* l) {
  __builtin_amdgcn_global_load_lds(
      (const __attribute__((address_space(1))) void*)g,
      (__attribute__((address_space(3))) void*)l, 16, 0, 0);
}

// ---------------------------------------------------------------------------
// fp32 -> bf16 elementwise convert (n must be multiple of 2048)
// ---------------------------------------------------------------------------
__global__ __launch_bounds__(256) void cvt_bf16_kernel(
    const float* __restrict__ in, __bf16* __restrict__ out) {
  const size_t i = ((size_t)blockIdx.x * 256 + threadIdx.x) * 8;
  const float4 v0 = *(const float4*)(in + i);
  const float4 v1 = *(const float4*)(in + i + 4);
  bf16x8 o;
  o[0] = (__bf16)v0.x; o[1] = (__bf16)v0.y; o[2] = (__bf16)v0.z; o[3] = (__bf16)v0.w;
  o[4] = (__bf16)v1.x; o[5] = (__bf16)v1.y; o[6] = (__bf16)v1.z; o[7] = (__bf16)v1.w;
  *(bf16x8*)(out + i) = o;
}

// ---------------------------------------------------------------------------
// Weight transpose + bf16 convert: T[n][k] = W[k][n]. grid (16,16,4)
// ---------------------------------------------------------------------------
__global__ __launch_bounds__(256) void transpose_w_kernel(
    const float* __restrict__ W0, const float* __restrict__ W1,
    const float* __restrict__ W2, const float* __restrict__ W3,
    __bf16* __restrict__ T0, __bf16* __restrict__ T1,
    __bf16* __restrict__ T2, __bf16* __restrict__ T3) {
  __shared__ __bf16 tile[64][65];
  const float* W;
  __bf16* T;
  switch (blockIdx.z) {
    case 0: W = W0; T = T0; break;
    case 1: W = W1; T = T1; break;
    case 2: W = W2; T = T2; break;
    default: W = W3; T = T3; break;
  }
  const int k0 = blockIdx.y * 64, n0 = blockIdx.x * 64;
  const int c = threadIdx.x & 63, rg = threadIdx.x >> 6;
#pragma unroll
  for (int i = 0; i < 16; i++) {
    const int r = rg + i * 4;
    tile[r][c] = (__bf16)W[(size_t)(k0 + r) * DD + n0 + c];
  }
  __syncthreads();
#pragma unroll
  for (int i = 0; i < 16; i++) {
    const int r = rg + i * 4;
    T[(size_t)(n0 + r) * DD + k0 + c] = tile[c][r];
  }
}

// ---------------------------------------------------------------------------
// m97-style GEMM core: C[128,128] += A[128,K] @ Bt[128,K]^T  (K = DD = 1024)
// 256 threads = 4 waves, each wave owns a 64x64 quadrant as 4x4 MFMA tiles.
// LDS: As/Bs [128][64] bf16 (unpadded — required by global_load_lds layout).
// ---------------------------------------------------------------------------
__device__ __forceinline__ void gemm_core(
    const __bf16* __restrict__ A, const __bf16* __restrict__ Bt,
    int bm, int bn, f32x4 (&acc)[4][4], __bf16* As, __bf16* Bs) {
  const int t = threadIdx.x;
  const int lane = t & 63, wave = t >> 6;
  const int col = lane & 15, quad = lane >> 4;
  const int wm = (wave & 1) * 64, wn = (wave >> 1) * 64;
  // staging: wave covers 32 rows (4 chunks of 8 rows / 1024 B)
  const int srow = wave * 32 + (lane >> 3);
  const int skol = (lane & 7) * 8;
  const __bf16* ag = A + (size_t)(bm + srow) * DD + skol;
  const __bf16* bg = Bt + (size_t)(bn + srow) * DD + skol;
  __bf16* asb = As + wave * 32 * 64;
  __bf16* bsb = Bs + wave * 32 * 64;

  for (int kt = 0; kt < DD; kt += 64) {
#pragma unroll
    for (int c = 0; c < 4; c++) {
      async_copy16(ag + (size_t)c * 8 * DD + kt, asb + c * 8 * 64);
      async_copy16(bg + (size_t)c * 8 * DD + kt, bsb + c * 8 * 64);
    }
    __syncthreads();  // compiler inserts vmcnt(0) drain here
#pragma unroll
    for (int ks = 0; ks < 2; ks++) {
      bf16x8 af[4], bf[4];
      const int k0 = ks * 32 + quad * 8;
#pragma unroll
      for (int i = 0; i < 4; i++)
        af[i] = *(const bf16x8*)(As + (wm + i * 16 + col) * 64 + k0);
#pragma unroll
      for (int j = 0; j < 4; j++)
        bf[j] = *(const bf16x8*)(Bs + (wn + j * 16 + col) * 64 + k0);
#pragma unroll
      for (int i = 0; i < 4; i++)
#pragma unroll
        for (int j = 0; j < 4; j++)
          acc[i][j] =
              __builtin_amdgcn_mfma_f32_16x16x32_bf16(af[i], bf[j], acc[i][j], 0, 0, 0);
    }
    __syncthreads();
  }
}

// ---------------------------------------------------------------------------
// Fused Q/K/V projection. grid (24, 32): blockIdx.x = mat*8 + n-tile.
// Epilogue: bias, RoPE (Q,K) via adjacent-lane shfl, scatter bf16 [B,H,S,DK].
// ---------------------------------------------------------------------------
__global__ __launch_bounds__(256) void qkv_gemm_kernel(
    const __bf16* __restrict__ xb, const __bf16* __restrict__ WqT,
    const __bf16* __restrict__ WkT, const __bf16* __restrict__ WvT,
    const float* __restrict__ bq, const float* __restrict__ bk,
    const float* __restrict__ bv, const int* __restrict__ pos,
    __bf16* __restrict__ qo, __bf16* __restrict__ ko, __bf16* __restrict__ vo) {
  __shared__ __bf16 As[128 * 64];
  __shared__ __bf16 Bs[128 * 64];
  const int mat = blockIdx.x >> 3;
  const int bn = (blockIdx.x & 7) * 128;
  const int bm = blockIdx.y * 128;
  const __bf16* Bt = mat == 0 ? WqT : (mat == 1 ? WkT : WvT);
  const float* bias = mat == 0 ? bq : (mat == 1 ? bk : bv);
  __bf16* out = mat == 0 ? qo : (mat == 1 ? ko : vo);

  f32x4 acc[4][4] = {};
  gemm_core(xb, Bt, bm, bn, acc, As, Bs);

  const int t = threadIdx.x, lane = t & 63, wave = t >> 6;
  const int col = lane & 15, quad = lane >> 4;
  const int wm = (wave & 1) * 64, wn = (wave >> 1) * 64;
  const bool rope = (mat < 2);
#pragma unroll
  for (int i = 0; i < 4; i++) {
#pragma unroll
    for (int j = 0; j < 4; j++) {
      const int n = bn + wn + j * 16 + col;
      const float bb = bias[n];
#pragma unroll
      for (int r = 0; r < 4; r++) {
        const int m = bm + wm + i * 16 + quad * 4 + r;
        float v = acc[i][j][r] + bb;
        if (rope) {
          const float other = __shfl_xor(v, 1, 64);
          const int pi = (n & 63) >> 1;
          // 10000^(-2*pi/64) = 2^(-pi * log2(10000)/32)
          const float inv = exp2f(-0.4152410118609203f * (float)pi);
          float sn, cs;
          __sincosf((float)pos[m] * inv, &sn, &cs);
          v = (n & 1) ? (other * sn + v * cs) : (v * cs - other * sn);
        }
        const int h = n >> 6, dk = n & 63;
        const int b = m >> 11, s = m & (SS - 1);
        out[((size_t)(b * HH + h) * SS + s) * DKK + dk] = (__bf16)v;
      }
    }
  }
}

// ---------------------------------------------------------------------------
// O projection: out[M,N] fp32 = ob[M,K] @ WoT[N,K]^T + bo. grid (8, 32).
// ---------------------------------------------------------------------------
__global__ __launch_bounds__(256) void oproj_gemm_kernel(
    const __bf16* __restrict__ ob, const __bf16* __restrict__ WoT,
    const float* __restrict__ bo, float* __restrict__ out) {
  __shared__ __bf16 As[128 * 64];
  __shared__ __bf16 Bs[128 * 64];
  const int bn = blockIdx.x * 128;
  const int bm = blockIdx.y * 128;
  f32x4 acc[4][4] = {};
  gemm_core(ob, WoT, bm, bn, acc, As, Bs);

  const int t = threadIdx.x, lane = t & 63, wave = t >> 6;
  const int col = lane & 15, quad = lane >> 4;
  const int wm = (wave & 1) * 64, wn = (wave >> 1) * 64;
#pragma unroll
  for (int i = 0; i < 4; i++) {
#pragma unroll
    for (int j = 0; j < 4; j++) {
      const int n = bn + wn + j * 16 + col;
      const float bb = bo[n];
#pragma unroll
      for (int r = 0; r < 4; r++) {
        const int m = bm + wm + i * 16 + quad * 4 + r;
        out[(size_t)m * DD + n] = acc[i][j][r] + bb;
      }
    }
  }
}

// ---------------------------------------------------------------------------
// Flash attention (causal, online softmax), unchanged structure from R1;
// now loads bf16 q/k/v and stores bf16 o.
// q,k,v in [B,H,S,DK] bf16; o written in [B,S,H,DK] bf16.
// ---------------------------------------------------------------------------
__global__ __launch_bounds__(256) void flash_attn_kernel(
    const __bf16* __restrict__ q, const __bf16* __restrict__ k,
    const __bf16* __restrict__ v, __bf16* __restrict__ o) {
  __shared__ float qsT[64][68];  // [dk][r]
  __shared__ float ksT[64][68];  // [dk][j]
  __shared__ float vs[64][68];   // [j][dk]
  __shared__ float sT[64][68];   // [j][r] scores, then probs
  __shared__ float mrow[64], lrow[64], arow[64];

  const int bh = blockIdx.x;   // 0..31
  const int qt = blockIdx.y;   // 0..31
  const int t  = threadIdx.x;
  const int r0 = (t >> 4) * 4;  // 0..60
  const int c0 = (t & 15) * 4;  // 0..60

  const __bf16* qb = q + (size_t)bh * SS * DKK;
  const __bf16* kb = k + (size_t)bh * SS * DKK;
  const __bf16* vb = v + (size_t)bh * SS * DKK;

#pragma unroll 4
  for (int i = 0; i < 16; i++) {
    const int idx = t + 256 * i;
    const int r  = idx >> 6;
    const int dk = idx & 63;
    qsT[dk][r] = (float)qb[(size_t)(qt * 64 + r) * DKK + dk];
  }
  if (t < 64) {
    mrow[t] = -1e30f;
    lrow[t] = 0.0f;
  }
  float oacc[4][4] = {};
  __syncthreads();

  for (int kt = 0; kt <= qt; kt++) {
#pragma unroll 4
    for (int i = 0; i < 16; i++) {
      const int idx = t + 256 * i;
      const int j  = idx >> 6;
      const int dk = idx & 63;
      const size_t g = (size_t)(kt * 64 + j) * DKK + dk;
      ksT[dk][j] = (float)kb[g];
      vs[j][dk]  = (float)vb[g];
    }
    __syncthreads();

    float sc[4][4] = {};
    for (int kk = 0; kk < 64; kk++) {
      float a[4], b4[4];
#pragma unroll
      for (int i = 0; i < 4; i++) a[i] = qsT[kk][r0 + i];
#pragma unroll
      for (int j = 0; j < 4; j++) b4[j] = ksT[kk][c0 + j];
#pragma unroll
      for (int i = 0; i < 4; i++)
#pragma unroll
        for (int j = 0; j < 4; j++) sc[i][j] += a[i] * b4[j];
    }
    const bool diag = (kt == qt);
#pragma unroll
    for (int j = 0; j < 4; j++)
#pragma unroll
      for (int i = 0; i < 4; i++) {
        float sv = sc[i][j] * kScale;
        if (diag && (c0 + j) > (r0 + i)) sv = -1e30f;
        sT[c0 + j][r0 + i] = sv;
      }
    __syncthreads();

    if (t < 64) {
      const float m_old = mrow[t];
      float mx = m_old;
      for (int j = 0; j < 64; j++) mx = fmaxf(mx, sT[j][t]);
      const float alpha = __expf(m_old - mx);
      float l = lrow[t] * alpha;
      for (int j = 0; j < 64; j++) {
        const float pj = __expf(sT[j][t] - mx);
        sT[j][t] = pj;
        l += pj;
      }
      mrow[t] = mx;
      lrow[t] = l;
      arow[t] = alpha;
    }
    __syncthreads();

    float al[4];
#pragma unroll
    for (int i = 0; i < 4; i++) al[i] = arow[r0 + i];
#pragma unroll
    for (int i = 0; i < 4; i++)
#pragma unroll
      for (int d = 0; d < 4; d++) oacc[i][d] *= al[i];
    for (int j = 0; j < 64; j++) {
      float p4[4], v4[4];
#pragma unroll
      for (int i = 0; i < 4; i++) p4[i] = sT[j][r0 + i];
#pragma unroll
      for (int d = 0; d < 4; d++) v4[d] = vs[j][c0 + d];
#pragma unroll
      for (int i = 0; i < 4; i++)
#pragma unroll
        for (int d = 0; d < 4; d++) oacc[i][d] += p4[i] * v4[d];
    }
    __syncthreads();
  }

  const int b = bh / HH;
  const int h = bh % HH;
#pragma unroll
  for (int i = 0; i < 4; i++) {
    const int s = qt * 64 + r0 + i;
    const float inv_l = 1.0f / lrow[r0 + i];
    __bf16* op = o + ((size_t)(b * SS + s) * HH + h) * DKK + c0;
#pragma unroll
    for (int d = 0; d < 4; d++) op[d] = (__bf16)(oacc[i][d] * inv_l);
  }
}

// ---------------------------------------------------------------------------
extern "C" void kernel_launch(void* const* d_in, const int* in_sizes, int n_in,
                              void* d_out, int out_size, void* d_ws,
                              size_t ws_size, hipStream_t stream) {
  const float* x  = (const float*)d_in[0];
  const int*  pos = (const int*)d_in[1];
  const float* Wq = (const float*)d_in[2];
  const float* bq = (const float*)d_in[3];
  const float* Wk = (const float*)d_in[4];
  const float* bk = (const float*)d_in[5];
  const float* Wv = (const float*)d_in[6];
  const float* bv = (const float*)d_in[7];
  const float* Wo = (const float*)d_in[8];
  const float* bo = (const float*)d_in[9];
  float* out = (float*)d_out;

  char* ws = (char*)d_ws;
  __bf16* xb  = (__bf16*)(ws);                          // 8 MB
  __bf16* WqT = (__bf16*)(ws + ((size_t)8  << 20));     // 2 MB each
  __bf16* WkT = (__bf16*)(ws + ((size_t)10 << 20));
  __bf16* WvT = (__bf16*)(ws + ((size_t)12 << 20));
  __bf16* WoT = (__bf16*)(ws + ((size_t)14 << 20));
  __bf16* qb  = (__bf16*)(ws + ((size_t)16 << 20));     // 8 MB each
  __bf16* kb  = (__bf16*)(ws + ((size_t)24 << 20));
  __bf16* vb  = (__bf16*)(ws + ((size_t)32 << 20));
  __bf16* ob  = (__bf16*)(ws + ((size_t)40 << 20));     // total 48 MB

  // x -> bf16 (4M elems, 8 per thread)
  cvt_bf16_kernel<<<2048, 256, 0, stream>>>(x, xb);
  // W -> bf16 transposed [N][K]
  transpose_w_kernel<<<dim3(16, 16, 4), 256, 0, stream>>>(Wq, Wk, Wv, Wo, WqT,
                                                          WkT, WvT, WoT);
  // Fused QKV projection + RoPE + scatter
  qkv_gemm_kernel<<<dim3(24, 32), 256, 0, stream>>>(xb, WqT, WkT, WvT, bq, bk,
                                                    bv, pos, qb, kb, vb);
  // Attention
  flash_attn_kernel<<<dim3(BB * HH, SS / 64), 256, 0, stream>>>(qb, kb, vb, ob);
  // Output projection
  oproj_gemm_kernel<<<dim3(8, 32), 256, 0, stream>>>(ob, WoT, bo, out);
}

// Round 3
// 298.770 us; speedup vs baseline: 3.9009x; 1.9163x over previous
//
#include <hip/hip_runtime.h>
#include <math.h>

// Problem constants
#define BB  2
#define SS  2048
#define DD  1024
#define HH  16
#define DKK 64

constexpr float kScale = 0.125f;  // 1/sqrt(64)

typedef __bf16 bf16x8 __attribute__((ext_vector_type(8)));
typedef float f32x4 __attribute__((ext_vector_type(4)));

// Async global->LDS, 16 B per lane. LDS dest must be WAVE-UNIFORM base;
// HW scatters lane i to base + i*16.
__device__ __forceinline__ void async_copy16(const void* g, void* l) {
  __builtin_amdgcn_global_load_lds(
      (const __attribute__((address_space(1))) void*)g,
      (__attribute__((address_space(3))) void*)l, 16, 0, 0);
}

// ---------------------------------------------------------------------------
// fp32 -> bf16 elementwise convert (n must be multiple of 2048)
// ---------------------------------------------------------------------------
__global__ __launch_bounds__(256) void cvt_bf16_kernel(
    const float* __restrict__ in, __bf16* __restrict__ out) {
  const size_t i = ((size_t)blockIdx.x * 256 + threadIdx.x) * 8;
  const float4 v0 = *(const float4*)(in + i);
  const float4 v1 = *(const float4*)(in + i + 4);
  bf16x8 o;
  o[0] = (__bf16)v0.x; o[1] = (__bf16)v0.y; o[2] = (__bf16)v0.z; o[3] = (__bf16)v0.w;
  o[4] = (__bf16)v1.x; o[5] = (__bf16)v1.y; o[6] = (__bf16)v1.z; o[7] = (__bf16)v1.w;
  *(bf16x8*)(out + i) = o;
}

// ---------------------------------------------------------------------------
// Weight transpose + bf16 convert: T[n][k] = W[k][n]. grid (16,16,4)
// ---------------------------------------------------------------------------
__global__ __launch_bounds__(256) void transpose_w_kernel(
    const float* __restrict__ W0, const float* __restrict__ W1,
    const float* __restrict__ W2, const float* __restrict__ W3,
    __bf16* __restrict__ T0, __bf16* __restrict__ T1,
    __bf16* __restrict__ T2, __bf16* __restrict__ T3) {
  __shared__ __bf16 tile[64][65];
  const float* W;
  __bf16* T;
  switch (blockIdx.z) {
    case 0: W = W0; T = T0; break;
    case 1: W = W1; T = T1; break;
    case 2: W = W2; T = T2; break;
    default: W = W3; T = T3; break;
  }
  const int k0 = blockIdx.y * 64, n0 = blockIdx.x * 64;
  const int c = threadIdx.x & 63, rg = threadIdx.x >> 6;
#pragma unroll
  for (int i = 0; i < 16; i++) {
    const int r = rg + i * 4;
    tile[r][c] = (__bf16)W[(size_t)(k0 + r) * DD + n0 + c];
  }
  __syncthreads();
#pragma unroll
  for (int i = 0; i < 16; i++) {
    const int r = rg + i * 4;
    T[(size_t)(n0 + r) * DD + k0 + c] = tile[c][r];
  }
}

// ---------------------------------------------------------------------------
// V transpose per head: vt[bh][d][s] = v[bh][s][d]. grid (32 s-tiles, 32 bh)
// ---------------------------------------------------------------------------
__global__ __launch_bounds__(256) void vtrans_kernel(
    const __bf16* __restrict__ v, __bf16* __restrict__ vt) {
  __shared__ __bf16 tile[64][72];
  const int st = blockIdx.x, bh = blockIdx.y;
  const __bf16* vb = v + (size_t)bh * SS * DKK + (size_t)st * 64 * DKK;
  __bf16* vo = vt + (size_t)bh * DKK * SS + st * 64;
  const int t = threadIdx.x;
  {
    const int r = t >> 2, c0 = (t & 3) * 16;
    bf16x8 a = *(const bf16x8*)(vb + r * DKK + c0);
    bf16x8 b = *(const bf16x8*)(vb + r * DKK + c0 + 8);
#pragma unroll
    for (int i = 0; i < 8; i++) tile[r][c0 + i] = a[i];
#pragma unroll
    for (int i = 0; i < 8; i++) tile[r][c0 + 8 + i] = b[i];
  }
  __syncthreads();
  {
    const int d = t >> 2, s0 = (t & 3) * 16;
    bf16x8 a, b;
#pragma unroll
    for (int i = 0; i < 8; i++) a[i] = tile[s0 + i][d];
#pragma unroll
    for (int i = 0; i < 8; i++) b[i] = tile[s0 + 8 + i][d];
    *(bf16x8*)(vo + (size_t)d * SS + s0) = a;
    *(bf16x8*)(vo + (size_t)d * SS + s0 + 8) = b;
  }
}

// ---------------------------------------------------------------------------
// m97-style GEMM core: C[128,128] += A[128,K] @ Bt[128,K]^T  (K = DD = 1024)
// ---------------------------------------------------------------------------
__device__ __forceinline__ void gemm_core(
    const __bf16* __restrict__ A, const __bf16* __restrict__ Bt,
    int bm, int bn, f32x4 (&acc)[4][4], __bf16* As, __bf16* Bs) {
  const int t = threadIdx.x;
  const int lane = t & 63, wave = t >> 6;
  const int col = lane & 15, quad = lane >> 4;
  const int wm = (wave & 1) * 64, wn = (wave >> 1) * 64;
  const int srow = wave * 32 + (lane >> 3);
  const int skol = (lane & 7) * 8;
  const __bf16* ag = A + (size_t)(bm + srow) * DD + skol;
  const __bf16* bg = Bt + (size_t)(bn + srow) * DD + skol;
  __bf16* asb = As + wave * 32 * 64;
  __bf16* bsb = Bs + wave * 32 * 64;

  for (int kt = 0; kt < DD; kt += 64) {
#pragma unroll
    for (int c = 0; c < 4; c++) {
      async_copy16(ag + (size_t)c * 8 * DD + kt, asb + c * 8 * 64);
      async_copy16(bg + (size_t)c * 8 * DD + kt, bsb + c * 8 * 64);
    }
    __syncthreads();
#pragma unroll
    for (int ks = 0; ks < 2; ks++) {
      bf16x8 af[4], bf[4];
      const int k0 = ks * 32 + quad * 8;
#pragma unroll
      for (int i = 0; i < 4; i++)
        af[i] = *(const bf16x8*)(As + (wm + i * 16 + col) * 64 + k0);
#pragma unroll
      for (int j = 0; j < 4; j++)
        bf[j] = *(const bf16x8*)(Bs + (wn + j * 16 + col) * 64 + k0);
#pragma unroll
      for (int i = 0; i < 4; i++)
#pragma unroll
        for (int j = 0; j < 4; j++)
          acc[i][j] =
              __builtin_amdgcn_mfma_f32_16x16x32_bf16(af[i], bf[j], acc[i][j], 0, 0, 0);
    }
    __syncthreads();
  }
}

// ---------------------------------------------------------------------------
// Fused Q/K/V projection. grid (24, 32): blockIdx.x = mat*8 + n-tile.
// ---------------------------------------------------------------------------
__global__ __launch_bounds__(256) void qkv_gemm_kernel(
    const __bf16* __restrict__ xb, const __bf16* __restrict__ WqT,
    const __bf16* __restrict__ WkT, const __bf16* __restrict__ WvT,
    const float* __restrict__ bq, const float* __restrict__ bk,
    const float* __restrict__ bv, const int* __restrict__ pos,
    __bf16* __restrict__ qo, __bf16* __restrict__ ko, __bf16* __restrict__ vo) {
  __shared__ __bf16 As[128 * 64];
  __shared__ __bf16 Bs[128 * 64];
  const int mat = blockIdx.x >> 3;
  const int bn = (blockIdx.x & 7) * 128;
  const int bm = blockIdx.y * 128;
  const __bf16* Bt = mat == 0 ? WqT : (mat == 1 ? WkT : WvT);
  const float* bias = mat == 0 ? bq : (mat == 1 ? bk : bv);
  __bf16* out = mat == 0 ? qo : (mat == 1 ? ko : vo);

  f32x4 acc[4][4] = {};
  gemm_core(xb, Bt, bm, bn, acc, As, Bs);

  const int t = threadIdx.x, lane = t & 63, wave = t >> 6;
  const int col = lane & 15, quad = lane >> 4;
  const int wm = (wave & 1) * 64, wn = (wave >> 1) * 64;
  const bool rope = (mat < 2);
#pragma unroll
  for (int i = 0; i < 4; i++) {
#pragma unroll
    for (int j = 0; j < 4; j++) {
      const int n = bn + wn + j * 16 + col;
      const float bb = bias[n];
#pragma unroll
      for (int r = 0; r < 4; r++) {
        const int m = bm + wm + i * 16 + quad * 4 + r;
        float v = acc[i][j][r] + bb;
        if (rope) {
          const float other = __shfl_xor(v, 1, 64);
          const int pi = (n & 63) >> 1;
          const float inv = exp2f(-0.4152410118609203f * (float)pi);
          float sn, cs;
          __sincosf((float)pos[m] * inv, &sn, &cs);
          v = (n & 1) ? (other * sn + v * cs) : (v * cs - other * sn);
        }
        const int h = n >> 6, dk = n & 63;
        const int b = m >> 11, s = m & (SS - 1);
        out[((size_t)(b * HH + h) * SS + s) * DKK + dk] = (__bf16)v;
      }
    }
  }
}

// ---------------------------------------------------------------------------
// O projection: out[M,N] fp32 = ob[M,K] @ WoT[N,K]^T + bo. grid (8, 32).
// ---------------------------------------------------------------------------
__global__ __launch_bounds__(256) void oproj_gemm_kernel(
    const __bf16* __restrict__ ob, const __bf16* __restrict__ WoT,
    const float* __restrict__ bo, float* __restrict__ out) {
  __shared__ __bf16 As[128 * 64];
  __shared__ __bf16 Bs[128 * 64];
  const int bn = blockIdx.x * 128;
  const int bm = blockIdx.y * 128;
  f32x4 acc[4][4] = {};
  gemm_core(ob, WoT, bm, bn, acc, As, Bs);

  const int t = threadIdx.x, lane = t & 63, wave = t >> 6;
  const int col = lane & 15, quad = lane >> 4;
  const int wm = (wave & 1) * 64, wn = (wave >> 1) * 64;
#pragma unroll
  for (int i = 0; i < 4; i++) {
#pragma unroll
    for (int j = 0; j < 4; j++) {
      const int n = bn + wn + j * 16 + col;
      const float bb = bo[n];
#pragma unroll
      for (int r = 0; r < 4; r++) {
        const int m = bm + wm + i * 16 + quad * 4 + r;
        out[(size_t)m * DD + n] = acc[i][j][r] + bb;
      }
    }
  }
}

// ---------------------------------------------------------------------------
// MFMA flash attention (causal, online softmax).
// Block = (bh, 128-row Q tile), 4 waves, each wave owns 32 Q-rows.
// K-tile = 64. q,k in [B,H,S,DK]; vt in [B,H,DK,S]; o out [B,S,H,DK] bf16.
// P goes C-layout -> LDS (wave-private) -> A-layout per m120 pattern.
// ---------------------------------------------------------------------------
__global__ __launch_bounds__(256) void flash_attn_mfma_kernel(
    const __bf16* __restrict__ q, const __bf16* __restrict__ k,
    const __bf16* __restrict__ vt, __bf16* __restrict__ o) {
  __shared__ __bf16 Ks[64 * 64];       // [token j][dk]
  __shared__ __bf16 Vs[64 * 64];       // [dk d][token j]
  __shared__ __bf16 Ps[4][32 * 64];    // per-wave [row][j]

  const int bh = blockIdx.x;   // 0..31
  const int qt = blockIdx.y;   // 0..15
  const int t = threadIdx.x, lane = t & 63, wave = t >> 6;
  const int col = lane & 15, quad = lane >> 4;

  const __bf16* qb = q + (size_t)bh * SS * DKK;
  const __bf16* kb = k + (size_t)bh * SS * DKK;
  const __bf16* vtb = vt + (size_t)bh * DKK * SS;

  const int rbase = qt * 128 + wave * 32;

  // Q fragments: A-layout, rows rt*16+col, k = ks*32+quad*8. Held all kernel.
  bf16x8 qf[2][2];
#pragma unroll
  for (int rt = 0; rt < 2; rt++)
#pragma unroll
    for (int ks = 0; ks < 2; ks++)
      qf[rt][ks] = *(const bf16x8*)(qb + (size_t)(rbase + rt * 16 + col) * DKK +
                                    ks * 32 + quad * 8);

  f32x4 oacc[2][4] = {};
  float m_s[2][4], l_s[2][4];
#pragma unroll
  for (int rt = 0; rt < 2; rt++)
#pragma unroll
    for (int r = 0; r < 4; r++) {
      m_s[rt][r] = -1e30f;
      l_s[rt][r] = 0.0f;
    }

  __bf16* pw = (__bf16*)Ps[wave];
  // staging lane mapping (per wave-issue: 8 rows x 128 B)
  const int r8 = lane >> 3;           // 0..7
  const int c8 = (lane & 7) * 8;      // element offset

  const int nkt = 2 * qt + 2;
  for (int kt = 0; kt < nkt; kt++) {
    // Stage K tile [64][64] and Vt tile [64][64]
#pragma unroll
    for (int i = 0; i < 2; i++) {
      const int row = (wave * 2 + i) * 8 + r8;
      async_copy16(kb + (size_t)(kt * 64 + row) * DKK + c8,
                   Ks + (wave * 2 + i) * 512);
      async_copy16(vtb + (size_t)row * SS + kt * 64 + c8,
                   Vs + (wave * 2 + i) * 512);
    }
    __syncthreads();

    // ---- QK^T: sc[rt][ct], D-row = quad*4+reg, D-col = col ----
    f32x4 sc[2][4] = {};
    {
      bf16x8 kf[4][2];
#pragma unroll
      for (int ct = 0; ct < 4; ct++)
#pragma unroll
        for (int ks = 0; ks < 2; ks++)
          kf[ct][ks] =
              *(const bf16x8*)(Ks + (ct * 16 + col) * 64 + ks * 32 + quad * 8);
#pragma unroll
      for (int rt = 0; rt < 2; rt++)
#pragma unroll
        for (int ct = 0; ct < 4; ct++)
#pragma unroll
          for (int ks = 0; ks < 2; ks++)
            sc[rt][ct] = __builtin_amdgcn_mfma_f32_16x16x32_bf16(
                qf[rt][ks], kf[ct][ks], sc[rt][ct], 0, 0, 0);
    }

    // ---- online softmax + P store ----
    const bool need_mask = (kt >= 2 * qt);
#pragma unroll
    for (int rt = 0; rt < 2; rt++) {
      float sv[4][4];
#pragma unroll
      for (int ct = 0; ct < 4; ct++)
#pragma unroll
        for (int r = 0; r < 4; r++) {
          float s = sc[rt][ct][r] * kScale;
          if (need_mask) {
            const int jg = kt * 64 + ct * 16 + col;
            const int rg = rbase + rt * 16 + quad * 4 + r;
            if (jg > rg) s = -1e30f;
          }
          sv[ct][r] = s;
        }
      float alpha[4];
#pragma unroll
      for (int r = 0; r < 4; r++) {
        float mx = fmaxf(fmaxf(sv[0][r], sv[1][r]), fmaxf(sv[2][r], sv[3][r]));
#pragma unroll
        for (int w = 1; w < 16; w <<= 1) mx = fmaxf(mx, __shfl_xor(mx, w, 64));
        const float mnew = fmaxf(m_s[rt][r], mx);
        alpha[r] = __expf(m_s[rt][r] - mnew);
        m_s[rt][r] = mnew;
      }
      float rs[4] = {0.f, 0.f, 0.f, 0.f};
#pragma unroll
      for (int ct = 0; ct < 4; ct++)
#pragma unroll
        for (int r = 0; r < 4; r++) {
          const float p = __expf(sv[ct][r] - m_s[rt][r]);
          rs[r] += p;
          pw[(rt * 16 + quad * 4 + r) * 64 + ct * 16 + col] = (__bf16)p;
        }
#pragma unroll
      for (int r = 0; r < 4; r++) {
#pragma unroll
        for (int w = 1; w < 16; w <<= 1) rs[r] += __shfl_xor(rs[r], w, 64);
        l_s[rt][r] = l_s[rt][r] * alpha[r] + rs[r];
      }
      // rescale O accumulator
#pragma unroll
      for (int dt = 0; dt < 4; dt++)
#pragma unroll
        for (int r = 0; r < 4; r++) oacc[rt][dt][r] *= alpha[r];
    }

    // ---- PV: O[rt][dt] += P @ Vt^T (wave-private P, no barrier needed) ----
    {
      bf16x8 vf[4][2], pf[2][2];
#pragma unroll
      for (int dt = 0; dt < 4; dt++)
#pragma unroll
        for (int ks = 0; ks < 2; ks++)
          vf[dt][ks] =
              *(const bf16x8*)(Vs + (dt * 16 + col) * 64 + ks * 32 + quad * 8);
#pragma unroll
      for (int rt = 0; rt < 2; rt++)
#pragma unroll
        for (int ks = 0; ks < 2; ks++)
          pf[rt][ks] =
              *(const bf16x8*)(pw + (rt * 16 + col) * 64 + ks * 32 + quad * 8);
#pragma unroll
      for (int rt = 0; rt < 2; rt++)
#pragma unroll
        for (int dt = 0; dt < 4; dt++)
#pragma unroll
          for (int ks = 0; ks < 2; ks++)
            oacc[rt][dt] = __builtin_amdgcn_mfma_f32_16x16x32_bf16(
                pf[rt][ks], vf[dt][ks], oacc[rt][dt], 0, 0, 0);
    }
    __syncthreads();
  }

  // Epilogue: normalize and write o [B,S,H,DK] bf16
  const int b = bh / HH, h = bh % HH;
#pragma unroll
  for (int rt = 0; rt < 2; rt++)
#pragma unroll
    for (int r = 0; r < 4; r++) {
      const float inv_l = 1.0f / l_s[rt][r];
      const int s = rbase + rt * 16 + quad * 4 + r;
#pragma unroll
      for (int dt = 0; dt < 4; dt++)
        o[((size_t)(b * SS + s) * HH + h) * DKK + dt * 16 + col] =
            (__bf16)(oacc[rt][dt][r] * inv_l);
    }
}

// ---------------------------------------------------------------------------
extern "C" void kernel_launch(void* const* d_in, const int* in_sizes, int n_in,
                              void* d_out, int out_size, void* d_ws,
                              size_t ws_size, hipStream_t stream) {
  const float* x  = (const float*)d_in[0];
  const int*  pos = (const int*)d_in[1];
  const float* Wq = (const float*)d_in[2];
  const float* bq = (const float*)d_in[3];
  const float* Wk = (const float*)d_in[4];
  const float* bk = (const float*)d_in[5];
  const float* Wv = (const float*)d_in[6];
  const float* bv = (const float*)d_in[7];
  const float* Wo = (const float*)d_in[8];
  const float* bo = (const float*)d_in[9];
  float* out = (float*)d_out;

  char* ws = (char*)d_ws;
  __bf16* xb  = (__bf16*)(ws);                          // 8 MB
  __bf16* WqT = (__bf16*)(ws + ((size_t)8  << 20));     // 2 MB each
  __bf16* WkT = (__bf16*)(ws + ((size_t)10 << 20));
  __bf16* WvT = (__bf16*)(ws + ((size_t)12 << 20));
  __bf16* WoT = (__bf16*)(ws + ((size_t)14 << 20));
  __bf16* qb  = (__bf16*)(ws + ((size_t)16 << 20));     // 8 MB each
  __bf16* kb  = (__bf16*)(ws + ((size_t)24 << 20));
  __bf16* vb  = (__bf16*)(ws + ((size_t)32 << 20));
  __bf16* vtb = (__bf16*)(ws + ((size_t)40 << 20));
  __bf16* ob  = (__bf16*)(ws + ((size_t)48 << 20));     // total 56 MB

  cvt_bf16_kernel<<<2048, 256, 0, stream>>>(x, xb);
  transpose_w_kernel<<<dim3(16, 16, 4), 256, 0, stream>>>(Wq, Wk, Wv, Wo, WqT,
                                                          WkT, WvT, WoT);
  qkv_gemm_kernel<<<dim3(24, 32), 256, 0, stream>>>(xb, WqT, WkT, WvT, bq, bk,
                                                    bv, pos, qb, kb, vb);
  vtrans_kernel<<<dim3(32, 32), 256, 0, stream>>>(vb, vtb);
  flash_attn_mfma_kernel<<<dim3(BB * HH, SS / 128), 256, 0, stream>>>(qb, kb,
                                                                      vtb, ob);
  oproj_gemm_kernel<<<dim3(8, 32), 256, 0, stream>>>(ob, WoT, bo, out);
}

// Round 4
// 248.126 us; speedup vs baseline: 4.6971x; 1.2041x over previous
//
#include <hip/hip_runtime.h>
#include <math.h>

// Problem constants
#define BB  2
#define SS  2048
#define DD  1024
#define HH  16
#define DKK 64

constexpr float kScale = 0.125f;  // 1/sqrt(64)

typedef __bf16 bf16x8 __attribute__((ext_vector_type(8)));
typedef float f32x4 __attribute__((ext_vector_type(4)));

// Async global->LDS, 16 B per lane. LDS dest must be WAVE-UNIFORM base;
// HW scatters lane i to base + i*16.
__device__ __forceinline__ void async_copy16(const void* g, void* l) {
  __builtin_amdgcn_global_load_lds(
      (const __attribute__((address_space(1))) void*)g,
      (__attribute__((address_space(3))) void*)l, 16, 0, 0);
}

// ---------------------------------------------------------------------------
// fp32 -> bf16 elementwise convert (n must be multiple of 2048)
// ---------------------------------------------------------------------------
__global__ __launch_bounds__(256) void cvt_bf16_kernel(
    const float* __restrict__ in, __bf16* __restrict__ out) {
  const size_t i = ((size_t)blockIdx.x * 256 + threadIdx.x) * 8;
  const float4 v0 = *(const float4*)(in + i);
  const float4 v1 = *(const float4*)(in + i + 4);
  bf16x8 o;
  o[0] = (__bf16)v0.x; o[1] = (__bf16)v0.y; o[2] = (__bf16)v0.z; o[3] = (__bf16)v0.w;
  o[4] = (__bf16)v1.x; o[5] = (__bf16)v1.y; o[6] = (__bf16)v1.z; o[7] = (__bf16)v1.w;
  *(bf16x8*)(out + i) = o;
}

// ---------------------------------------------------------------------------
// Weight transpose + bf16 convert: T[n][k] = W[k][n]. grid (16,16,4)
// ---------------------------------------------------------------------------
__global__ __launch_bounds__(256) void transpose_w_kernel(
    const float* __restrict__ W0, const float* __restrict__ W1,
    const float* __restrict__ W2, const float* __restrict__ W3,
    __bf16* __restrict__ T0, __bf16* __restrict__ T1,
    __bf16* __restrict__ T2, __bf16* __restrict__ T3) {
  __shared__ __bf16 tile[64][65];
  const float* W;
  __bf16* T;
  switch (blockIdx.z) {
    case 0: W = W0; T = T0; break;
    case 1: W = W1; T = T1; break;
    case 2: W = W2; T = T2; break;
    default: W = W3; T = T3; break;
  }
  const int k0 = blockIdx.y * 64, n0 = blockIdx.x * 64;
  const int c = threadIdx.x & 63, rg = threadIdx.x >> 6;
#pragma unroll
  for (int i = 0; i < 16; i++) {
    const int r = rg + i * 4;
    tile[r][c] = (__bf16)W[(size_t)(k0 + r) * DD + n0 + c];
  }
  __syncthreads();
#pragma unroll
  for (int i = 0; i < 16; i++) {
    const int r = rg + i * 4;
    T[(size_t)(n0 + r) * DD + k0 + c] = tile[c][r];
  }
}

// ---------------------------------------------------------------------------
// V transpose per head: vt[bh][d][s] = v[bh][s][d]. grid (32 s-tiles, 32 bh)
// ---------------------------------------------------------------------------
__global__ __launch_bounds__(256) void vtrans_kernel(
    const __bf16* __restrict__ v, __bf16* __restrict__ vt) {
  __shared__ __bf16 tile[64][72];
  const int st = blockIdx.x, bh = blockIdx.y;
  const __bf16* vb = v + (size_t)bh * SS * DKK + (size_t)st * 64 * DKK;
  __bf16* vo = vt + (size_t)bh * DKK * SS + st * 64;
  const int t = threadIdx.x;
  {
    const int r = t >> 2, c0 = (t & 3) * 16;
    bf16x8 a = *(const bf16x8*)(vb + r * DKK + c0);
    bf16x8 b = *(const bf16x8*)(vb + r * DKK + c0 + 8);
#pragma unroll
    for (int i = 0; i < 8; i++) tile[r][c0 + i] = a[i];
#pragma unroll
    for (int i = 0; i < 8; i++) tile[r][c0 + 8 + i] = b[i];
  }
  __syncthreads();
  {
    const int d = t >> 2, s0 = (t & 3) * 16;
    bf16x8 a, b;
#pragma unroll
    for (int i = 0; i < 8; i++) a[i] = tile[s0 + i][d];
#pragma unroll
    for (int i = 0; i < 8; i++) b[i] = tile[s0 + 8 + i][d];
    *(bf16x8*)(vo + (size_t)d * SS + s0) = a;
    *(bf16x8*)(vo + (size_t)d * SS + s0 + 8) = b;
  }
}

// ---------------------------------------------------------------------------
// m97-style GEMM core with XOR chunk-swizzled LDS (conflict-free B-frag reads)
// C[128,128] += A[128,K] @ Bt[128,K]^T  (K = DD = 1024)
// LDS row r holds global chunk c at LDS chunk c^(r&7)  (chunk = 8 bf16 = 16 B)
// ---------------------------------------------------------------------------
__device__ __forceinline__ void gemm_core(
    const __bf16* __restrict__ A, const __bf16* __restrict__ Bt,
    int bm, int bn, f32x4 (&acc)[4][4], __bf16* As, __bf16* Bs) {
  const int t = threadIdx.x;
  const int lane = t & 63, wave = t >> 6;
  const int col = lane & 15, quad = lane >> 4;
  const int wm = (wave & 1) * 64, wn = (wave >> 1) * 64;
  const int r8 = lane >> 3;             // row within 8-row slab
  const int cg = (lane & 7) ^ r8;       // swizzled global chunk
  const __bf16* ag = A + (size_t)(bm + wave * 32 + r8) * DD + cg * 8;
  const __bf16* bg = Bt + (size_t)(bn + wave * 32 + r8) * DD + cg * 8;
  __bf16* asb = As + wave * 32 * 64;
  __bf16* bsb = Bs + wave * 32 * 64;

  for (int kt = 0; kt < DD; kt += 64) {
#pragma unroll
    for (int c = 0; c < 4; c++) {
      async_copy16(ag + (size_t)c * 8 * DD + kt, asb + c * 512);
      async_copy16(bg + (size_t)c * 8 * DD + kt, bsb + c * 512);
    }
    __syncthreads();
#pragma unroll
    for (int ks = 0; ks < 2; ks++) {
      bf16x8 af[4], bf[4];
#pragma unroll
      for (int i = 0; i < 4; i++)
        af[i] = *(const bf16x8*)(As + (wm + i * 16 + col) * 64 +
                                 (((ks * 4 + quad) ^ (col & 7)) * 8));
#pragma unroll
      for (int j = 0; j < 4; j++)
        bf[j] = *(const bf16x8*)(Bs + (wn + j * 16 + col) * 64 +
                                 (((ks * 4 + quad) ^ (col & 7)) * 8));
#pragma unroll
      for (int i = 0; i < 4; i++)
#pragma unroll
        for (int j = 0; j < 4; j++)
          acc[i][j] =
              __builtin_amdgcn_mfma_f32_16x16x32_bf16(af[i], bf[j], acc[i][j], 0, 0, 0);
    }
    __syncthreads();
  }
}

// ---------------------------------------------------------------------------
// Fused Q/K/V projection. grid (24, 32): blockIdx.x = mat*8 + n-tile.
// ---------------------------------------------------------------------------
__global__ __launch_bounds__(256) void qkv_gemm_kernel(
    const __bf16* __restrict__ xb, const __bf16* __restrict__ WqT,
    const __bf16* __restrict__ WkT, const __bf16* __restrict__ WvT,
    const float* __restrict__ bq, const float* __restrict__ bk,
    const float* __restrict__ bv, const int* __restrict__ pos,
    __bf16* __restrict__ qo, __bf16* __restrict__ ko, __bf16* __restrict__ vo) {
  __shared__ __bf16 As[128 * 64];
  __shared__ __bf16 Bs[128 * 64];
  const int mat = blockIdx.x >> 3;
  const int bn = (blockIdx.x & 7) * 128;
  const int bm = blockIdx.y * 128;
  const __bf16* Bt = mat == 0 ? WqT : (mat == 1 ? WkT : WvT);
  const float* bias = mat == 0 ? bq : (mat == 1 ? bk : bv);
  __bf16* out = mat == 0 ? qo : (mat == 1 ? ko : vo);

  f32x4 acc[4][4] = {};
  gemm_core(xb, Bt, bm, bn, acc, As, Bs);

  const int t = threadIdx.x, lane = t & 63, wave = t >> 6;
  const int col = lane & 15, quad = lane >> 4;
  const int wm = (wave & 1) * 64, wn = (wave >> 1) * 64;
  const bool rope = (mat < 2);
#pragma unroll
  for (int i = 0; i < 4; i++) {
#pragma unroll
    for (int j = 0; j < 4; j++) {
      const int n = bn + wn + j * 16 + col;
      const float bb = bias[n];
#pragma unroll
      for (int r = 0; r < 4; r++) {
        const int m = bm + wm + i * 16 + quad * 4 + r;
        float v = acc[i][j][r] + bb;
        if (rope) {
          const float other = __shfl_xor(v, 1, 64);
          const int pi = (n & 63) >> 1;
          const float inv = exp2f(-0.4152410118609203f * (float)pi);
          float sn, cs;
          __sincosf((float)pos[m] * inv, &sn, &cs);
          v = (n & 1) ? (other * sn + v * cs) : (v * cs - other * sn);
        }
        const int h = n >> 6, dk = n & 63;
        const int b = m >> 11, s = m & (SS - 1);
        out[((size_t)(b * HH + h) * SS + s) * DKK + dk] = (__bf16)v;
      }
    }
  }
}

// ---------------------------------------------------------------------------
// O projection: out[M,N] fp32 = ob[M,K] @ WoT[N,K]^T + bo. grid (8, 32).
// ---------------------------------------------------------------------------
__global__ __launch_bounds__(256) void oproj_gemm_kernel(
    const __bf16* __restrict__ ob, const __bf16* __restrict__ WoT,
    const float* __restrict__ bo, float* __restrict__ out) {
  __shared__ __bf16 As[128 * 64];
  __shared__ __bf16 Bs[128 * 64];
  const int bn = blockIdx.x * 128;
  const int bm = blockIdx.y * 128;
  f32x4 acc[4][4] = {};
  gemm_core(ob, WoT, bm, bn, acc, As, Bs);

  const int t = threadIdx.x, lane = t & 63, wave = t >> 6;
  const int col = lane & 15, quad = lane >> 4;
  const int wm = (wave & 1) * 64, wn = (wave >> 1) * 64;
#pragma unroll
  for (int i = 0; i < 4; i++) {
#pragma unroll
    for (int j = 0; j < 4; j++) {
      const int n = bn + wn + j * 16 + col;
      const float bb = bo[n];
#pragma unroll
      for (int r = 0; r < 4; r++) {
        const int m = bm + wm + i * 16 + quad * 4 + r;
        out[(size_t)m * DD + n] = acc[i][j][r] + bb;
      }
    }
  }
}

// ---------------------------------------------------------------------------
// MFMA flash attention, load-balanced: block = (bh, pair p).
// Processes 64-row Q-tile p, then Q-tile 31-p: (p+1)+(32-p) = 33 iters const.
// 4 waves, each owns 16 Q-rows. K-tile = 64 cols.
// Ks/Vs use XOR chunk swizzle (conflict-free); Ps padded to stride 72.
// q,k in [B,H,S,DK]; vt in [B,H,DK,S]; o out [B,S,H,DK] bf16.
// ---------------------------------------------------------------------------
__global__ __launch_bounds__(256) void flash_attn_mfma_kernel(
    const __bf16* __restrict__ q, const __bf16* __restrict__ k,
    const __bf16* __restrict__ vt, __bf16* __restrict__ o) {
  __shared__ __bf16 Ks[64 * 64];       // [j][dk], chunk-swizzled
  __shared__ __bf16 Vs[64 * 64];       // [d][j],  chunk-swizzled
  __shared__ __bf16 Ps[4][16 * 72];    // per-wave [row][j], stride 72

  const int bh = blockIdx.x;   // 0..31
  const int pr = blockIdx.y;   // 0..15
  const int t = threadIdx.x, lane = t & 63, wave = t >> 6;
  const int col = lane & 15, quad = lane >> 4;
  const int r8 = lane >> 3;            // row in 8-row slab
  const int cg = (lane & 7) ^ r8;      // swizzled global chunk

  const __bf16* qb = q + (size_t)bh * SS * DKK;
  const __bf16* kb = k + (size_t)bh * SS * DKK;
  const __bf16* vtb = vt + (size_t)bh * DKK * SS;
  const int b = bh / HH, h = bh % HH;
  __bf16* pw = (__bf16*)Ps[wave];

#pragma unroll
  for (int phase = 0; phase < 2; phase++) {
    const int qt = phase == 0 ? pr : (31 - pr);
    const int rbase = qt * 64 + wave * 16;

    // Q fragments for this phase (held in registers)
    bf16x8 qf[2];
#pragma unroll
    for (int ks = 0; ks < 2; ks++)
      qf[ks] = *(const bf16x8*)(qb + (size_t)(rbase + col) * DKK + ks * 32 +
                                quad * 8);

    f32x4 oacc[4] = {};
    float m_s[4], l_s[4];
#pragma unroll
    for (int r = 0; r < 4; r++) {
      m_s[r] = -1e30f;
      l_s[r] = 0.0f;
    }

    for (int kt = 0; kt <= qt; kt++) {
      // Stage K tile [64][64] and Vt tile [64][64]; wave w covers slabs
      // w*2 and w*2+1 (8 rows each).
#pragma unroll
      for (int i = 0; i < 2; i++) {
        const int slab = wave * 2 + i;
        async_copy16(kb + (size_t)(kt * 64 + slab * 8 + r8) * DKK + cg * 8,
                     Ks + slab * 512);
        async_copy16(vtb + (size_t)(slab * 8 + r8) * SS + kt * 64 + cg * 8,
                     Vs + slab * 512);
      }
      __syncthreads();

      // ---- QK^T: sc[ct], D-row = quad*4+reg, D-col = ct*16+col ----
      f32x4 sc[4] = {};
#pragma unroll
      for (int ct = 0; ct < 4; ct++)
#pragma unroll
        for (int ks = 0; ks < 2; ks++) {
          const bf16x8 kf = *(const bf16x8*)(Ks + (ct * 16 + col) * 64 +
                                             (((ks * 4 + quad) ^ (col & 7)) * 8));
          sc[ct] = __builtin_amdgcn_mfma_f32_16x16x32_bf16(qf[ks], kf, sc[ct],
                                                           0, 0, 0);
        }

      // ---- online softmax + P store ----
      const bool need_mask = (kt == qt);
      float sv[4][4];
#pragma unroll
      for (int ct = 0; ct < 4; ct++)
#pragma unroll
        for (int r = 0; r < 4; r++) {
          float s = sc[ct][r] * kScale;
          if (need_mask) {
            const int jg = kt * 64 + ct * 16 + col;
            const int rg = rbase + quad * 4 + r;
            if (jg > rg) s = -1e30f;
          }
          sv[ct][r] = s;
        }
      float alpha[4];
#pragma unroll
      for (int r = 0; r < 4; r++) {
        float mx = fmaxf(fmaxf(sv[0][r], sv[1][r]), fmaxf(sv[2][r], sv[3][r]));
#pragma unroll
        for (int w = 1; w < 16; w <<= 1) mx = fmaxf(mx, __shfl_xor(mx, w, 64));
        const float mnew = fmaxf(m_s[r], mx);
        alpha[r] = __expf(m_s[r] - mnew);
        m_s[r] = mnew;
      }
      float rs[4] = {0.f, 0.f, 0.f, 0.f};
#pragma unroll
      for (int ct = 0; ct < 4; ct++)
#pragma unroll
        for (int r = 0; r < 4; r++) {
          const float p = __expf(sv[ct][r] - m_s[r]);
          rs[r] += p;
          pw[(quad * 4 + r) * 72 + ct * 16 + col] = (__bf16)p;
        }
#pragma unroll
      for (int r = 0; r < 4; r++) {
#pragma unroll
        for (int w = 1; w < 16; w <<= 1) rs[r] += __shfl_xor(rs[r], w, 64);
        l_s[r] = l_s[r] * alpha[r] + rs[r];
      }
#pragma unroll
      for (int dt = 0; dt < 4; dt++)
#pragma unroll
        for (int r = 0; r < 4; r++) oacc[dt][r] *= alpha[r];

      // ---- PV: O[16 rows][dt*16+col] += P @ Vt^T (wave-private P) ----
      {
        bf16x8 pf[2];
#pragma unroll
        for (int ks = 0; ks < 2; ks++)
          pf[ks] = *(const bf16x8*)(pw + col * 72 + ks * 32 + quad * 8);
#pragma unroll
        for (int dt = 0; dt < 4; dt++)
#pragma unroll
          for (int ks = 0; ks < 2; ks++) {
            const bf16x8 vf = *(const bf16x8*)(Vs + (dt * 16 + col) * 64 +
                                               (((ks * 4 + quad) ^ (col & 7)) * 8));
            oacc[dt] = __builtin_amdgcn_mfma_f32_16x16x32_bf16(pf[ks], vf,
                                                               oacc[dt], 0, 0, 0);
          }
      }
      __syncthreads();
    }

    // Phase epilogue: normalize and write o [B,S,H,DK] bf16
#pragma unroll
    for (int r = 0; r < 4; r++) {
      const float inv_l = 1.0f / l_s[r];
      const int s = rbase + quad * 4 + r;
#pragma unroll
      for (int dt = 0; dt < 4; dt++)
        o[((size_t)(b * SS + s) * HH + h) * DKK + dt * 16 + col] =
            (__bf16)(oacc[dt][r] * inv_l);
    }
  }
}

// ---------------------------------------------------------------------------
extern "C" void kernel_launch(void* const* d_in, const int* in_sizes, int n_in,
                              void* d_out, int out_size, void* d_ws,
                              size_t ws_size, hipStream_t stream) {
  const float* x  = (const float*)d_in[0];
  const int*  pos = (const int*)d_in[1];
  const float* Wq = (const float*)d_in[2];
  const float* bq = (const float*)d_in[3];
  const float* Wk = (const float*)d_in[4];
  const float* bk = (const float*)d_in[5];
  const float* Wv = (const float*)d_in[6];
  const float* bv = (const float*)d_in[7];
  const float* Wo = (const float*)d_in[8];
  const float* bo = (const float*)d_in[9];
  float* out = (float*)d_out;

  char* ws = (char*)d_ws;
  __bf16* xb  = (__bf16*)(ws);                          // 8 MB
  __bf16* WqT = (__bf16*)(ws + ((size_t)8  << 20));     // 2 MB each
  __bf16* WkT = (__bf16*)(ws + ((size_t)10 << 20));
  __bf16* WvT = (__bf16*)(ws + ((size_t)12 << 20));
  __bf16* WoT = (__bf16*)(ws + ((size_t)14 << 20));
  __bf16* qb  = (__bf16*)(ws + ((size_t)16 << 20));     // 8 MB each
  __bf16* kb  = (__bf16*)(ws + ((size_t)24 << 20));
  __bf16* vb  = (__bf16*)(ws + ((size_t)32 << 20));
  __bf16* vtb = (__bf16*)(ws + ((size_t)40 << 20));
  __bf16* ob  = (__bf16*)(ws + ((size_t)48 << 20));     // total 56 MB

  cvt_bf16_kernel<<<2048, 256, 0, stream>>>(x, xb);
  transpose_w_kernel<<<dim3(16, 16, 4), 256, 0, stream>>>(Wq, Wk, Wv, Wo, WqT,
                                                          WkT, WvT, WoT);
  qkv_gemm_kernel<<<dim3(24, 32), 256, 0, stream>>>(xb, WqT, WkT, WvT, bq, bk,
                                                    bv, pos, qb, kb, vb);
  vtrans_kernel<<<dim3(32, 32), 256, 0, stream>>>(vb, vtb);
  flash_attn_mfma_kernel<<<dim3(BB * HH, 16), 256, 0, stream>>>(qb, kb, vtb,
                                                                ob);
  oproj_gemm_kernel<<<dim3(8, 32), 256, 0, stream>>>(ob, WoT, bo, out);
}